// Round 4
// baseline (312.800 us; speedup 1.0000x reference)
//
#include <hip/hip_runtime.h>

#define GLOBAL_AS __attribute__((address_space(1)))
#define LDS_AS    __attribute__((address_space(3)))

typedef __bf16 bf16x8 __attribute__((ext_vector_type(8)));
typedef float  f32x16 __attribute__((ext_vector_type(16)));
typedef unsigned short u16x4 __attribute__((ext_vector_type(4)));

// ---------- helpers ----------
__device__ inline unsigned short f2bf(float f) {
    unsigned int u = __float_as_uint(f);
    return (unsigned short)((u + 0x7fffu + ((u >> 16) & 1u)) >> 16);  // RNE
}

// ---------- kernel 1: fused L2 normalize (audio then visual), 1 wave/row ----------
__global__ __launch_bounds__(256) void l2norm_kernel(const float* __restrict__ audio,
                                                     const float* __restrict__ visual,
                                                     unsigned short* __restrict__ out) {
    const int gw = blockIdx.x * 4 + (threadIdx.x >> 6);  // global row 0..24575
    const int l  = threadIdx.x & 63;
    const float* src = (gw < 16384) ? (audio + (size_t)gw * 768)
                                    : (visual + ((size_t)gw - 16384) * 768);
    const float4* p = (const float4*)src;
    float4 a = p[l], b = p[l + 64], c = p[l + 128];
    float ss = a.x * a.x + a.y * a.y + a.z * a.z + a.w * a.w
             + b.x * b.x + b.y * b.y + b.z * b.z + b.w * b.w
             + c.x * c.x + c.y * c.y + c.z * c.z + c.w * c.w;
#pragma unroll
    for (int m = 1; m < 64; m <<= 1) ss += __shfl_xor(ss, m, 64);
    const float s = 1.0f / fmaxf(sqrtf(ss), 1e-12f);
    u16x4* o = (u16x4*)(out + (size_t)gw * 768);
    u16x4 u0 = {f2bf(a.x * s), f2bf(a.y * s), f2bf(a.z * s), f2bf(a.w * s)};
    u16x4 u1 = {f2bf(b.x * s), f2bf(b.y * s), f2bf(b.z * s), f2bf(b.w * s)};
    u16x4 u2 = {f2bf(c.x * s), f2bf(c.y * s), f2bf(c.z * s), f2bf(c.w * s)};
    o[l] = u0; o[l + 64] = u1; o[l + 128] = u2;
}

// ---------- kernel 2: 256x256-tile, 4-phase/K-tile, 32x32x16 MFMA, fused row-max ----
// A: 16384x768 bf16, V: 8192x768 bf16. Block = 256 audio rows x one clip (256 visual).
// LDS: A dbuf{0,1} x half{0,1} @ (buf*2+h)*16384 ; B same @ +65536. Half = 128x64 bf16.
// Swizzle: phys_cb = logical_cb ^ ((row&7)<<4); stage = linear dest + inv-swz source.
// Schedule per K-tile kt (buf = kt&1): phases P0..P3, one barrier each:
//   Pp: lgkmcnt(0); 8x mfma_32x32x16 (k-step p); ds_read k-step p+1; barrier
//   P3 additionally: stage ALL 4 half-tiles of kt+2 (same buf; every last read of
//   this buf happened <= P2, >=1 barrier before the stores can land -> race-free);
//   then vmcnt(8) (kt+1 landed; kt+2's 8 loads outstanding); barrier; prefetch
//   next tile's k-step-0 fragments (other buf, now visible).

#define STAGE_A(KTJ, H) do {                                                          \
    const int _sb = (KTJ) & 1;                                                        \
    char* _ld = smem + ((((_sb) << 1) + (H)) << 14) + stageOff;                       \
    const size_t _go = (size_t)((H) * 196608) + (size_t)((KTJ) * 128);                \
    __builtin_amdgcn_global_load_lds((GLOBAL_AS void*)(aSrc0 + _go),                  \
                                     (LDS_AS void*)(_ld), 16, 0, 0);                  \
    __builtin_amdgcn_global_load_lds((GLOBAL_AS void*)(aSrc1 + _go),                  \
                                     (LDS_AS void*)(_ld + 8192), 16, 0, 0);           \
  } while (0)

#define STAGE_B(KTJ, H) do {                                                          \
    const int _sb = (KTJ) & 1;                                                        \
    char* _ld = smem + 65536 + ((((_sb) << 1) + (H)) << 14) + stageOff;               \
    const size_t _go = (size_t)((H) * 196608) + (size_t)((KTJ) * 128);                \
    __builtin_amdgcn_global_load_lds((GLOBAL_AS void*)(vSrc0 + _go),                  \
                                     (LDS_AS void*)(_ld), 16, 0, 0);                  \
    __builtin_amdgcn_global_load_lds((GLOBAL_AS void*)(vSrc1 + _go),                  \
                                     (LDS_AS void*)(_ld + 8192), 16, 0, 0);           \
  } while (0)

#define PHASE_BAR() do {                                                              \
    __builtin_amdgcn_sched_barrier(0);                                                \
    __builtin_amdgcn_s_barrier();                                                     \
    __builtin_amdgcn_sched_barrier(0);                                                \
  } while (0)

// read k-step KS fragments into set DST: 4 A-frags + 2 B-frags (6x ds_read_b128)
#define READ_AB(DST, AT, BT, KS) do {                                                 \
    const char* _ap = (AT) + aLane + cbks[KS];                                        \
    const char* _bp = (BT) + bLane + cbks[KS];                                        \
    fa[DST][0] = *(const bf16x8*)(_ap);                                               \
    fa[DST][1] = *(const bf16x8*)(_ap + 4096);                                        \
    fa[DST][2] = *(const bf16x8*)(_ap + 8192);                                        \
    fa[DST][3] = *(const bf16x8*)(_ap + 12288);                                       \
    fb[DST][0] = *(const bf16x8*)(_bp);                                               \
    fb[DST][1] = *(const bf16x8*)(_bp + 4096);                                        \
  } while (0)

#define MFMA8(SRC) do {                                                               \
    asm volatile("s_waitcnt lgkmcnt(0)" ::: "memory");                                \
    __builtin_amdgcn_sched_barrier(0);                                                \
    __builtin_amdgcn_s_setprio(1);                                                    \
    _Pragma("unroll") for (int _mi = 0; _mi < 4; ++_mi)                               \
      _Pragma("unroll") for (int _ni = 0; _ni < 2; ++_ni)                             \
        acc[_mi][_ni] = __builtin_amdgcn_mfma_f32_32x32x16_bf16(                      \
            fa[SRC][_mi], fb[SRC][_ni], acc[_mi][_ni], 0, 0, 0);                      \
    __builtin_amdgcn_s_setprio(0);                                                    \
    __builtin_amdgcn_sched_barrier(0);                                                \
  } while (0)

#define KTILE(KT, DOSTAGE, VMN, DOREADNEXT) do {                                      \
    const int _buf = (KT) & 1;                                                        \
    const char* _aT  = smem + (((_buf << 1) + wm) << 14);                             \
    const char* _bT  = smem + 65536 + (((_buf << 1) + (wn >> 1)) << 14);              \
    const char* _aTn = smem + ((((1 - _buf) << 1) + wm) << 14);                       \
    const char* _bTn = smem + 65536 + ((((1 - _buf) << 1) + (wn >> 1)) << 14);        \
    /* P0 */ MFMA8(0); READ_AB(1, _aT, _bT, 1); PHASE_BAR();                          \
    /* P1 */ MFMA8(1); READ_AB(0, _aT, _bT, 2); PHASE_BAR();                          \
    /* P2 */ MFMA8(0); READ_AB(1, _aT, _bT, 3); PHASE_BAR();                          \
    /* P3 */ MFMA8(1);                                                                \
    if (DOSTAGE) {                                                                    \
      STAGE_A((KT) + 2, 0); STAGE_A((KT) + 2, 1);                                     \
      STAGE_B((KT) + 2, 0); STAGE_B((KT) + 2, 1);                                     \
    }                                                                                 \
    if ((VMN) == 8)      asm volatile("s_waitcnt vmcnt(8)" ::: "memory");             \
    else if ((VMN) == 0) asm volatile("s_waitcnt vmcnt(0)" ::: "memory");             \
    PHASE_BAR();                                                                      \
    if (DOREADNEXT) { READ_AB(0, _aTn, _bTn, 0); }                                    \
  } while (0)

__global__ __launch_bounds__(512, 2) void gemm_max_kernel(
    const unsigned short* __restrict__ A, const unsigned short* __restrict__ V,
    float* __restrict__ rowmax) {
    __shared__ __align__(1024) char smem[131072];

    const int tid = threadIdx.x;
    const int l   = tid & 63;
    const int wid = tid >> 6;
    const int wm  = wid >> 2;      // 0..1 : 128-row half of A tile
    const int wn  = wid & 3;       // 0..3 : 64-col slice of B tile
    const int lo5 = l & 31;
    const int hi  = l >> 5;        // k-half within frag
    // per-k-step swizzled column-byte offsets (logical kb = ks*32 + hi*16)
    int cbks[4];
#pragma unroll
    for (int ks = 0; ks < 4; ++ks)
        cbks[ks] = (ks * 32 + hi * 16) ^ ((l & 7) << 4);
    const int aLane = lo5 * 128;
    const int bLane = (wn & 1) * 8192 + lo5 * 128;
    const int stageOff = wid * 1024;

    const int bx  = blockIdx.x;                  // 2048 blocks, %8==0 -> bijective
    const int swz = (bx & 7) * 256 + (bx >> 3);  // XCD-aware swizzle
    const int rowBlk = swz >> 5;                 // 0..63
    const int clip   = swz & 31;                 // 0..31
    const size_t aRow0 = (size_t)rowBlk * 256;
    const size_t vRow0 = (size_t)clip * 256;

    // staging sources: linear LDS offset o (row=o>>7, cb=o&127) <- global element
    // at (row, cb ^ ((row&7)<<4)); chunk1 = +64 rows (64%8==0 -> same swizzle term).
    const char *aSrc0, *aSrc1, *vSrc0, *vSrc1;
    {
        const int r0 = tid >> 3;                                     // 0..63
        const int cb = ((tid & 7) * 16) ^ ((r0 & 7) << 4);
        aSrc0 = (const char*)A + (aRow0 + r0) * 1536 + cb;
        aSrc1 = aSrc0 + 64 * 1536;
        vSrc0 = (const char*)V + (vRow0 + r0) * 1536 + cb;
        vSrc1 = vSrc0 + 64 * 1536;
    }

    f32x16 acc[4][2];
#pragma unroll
    for (int i = 0; i < 4; ++i)
#pragma unroll
        for (int j = 0; j < 2; ++j)
#pragma unroll
            for (int r = 0; r < 16; ++r) acc[i][j][r] = 0.0f;

    bf16x8 fa[2][4], fb[2][2];

    // prologue: stage kt0 + kt1 fully (16 loads); wait kt0 (8 newest = kt1 in flight)
    STAGE_A(0, 0); STAGE_A(0, 1); STAGE_B(0, 0); STAGE_B(0, 1);
    STAGE_A(1, 0); STAGE_A(1, 1); STAGE_B(1, 0); STAGE_B(1, 1);
    asm volatile("s_waitcnt vmcnt(8)" ::: "memory");
    PHASE_BAR();
    {
        const char* _aT = smem + (wm << 14);
        const char* _bT = smem + 65536 + ((wn >> 1) << 14);
        READ_AB(0, _aT, _bT, 0);
    }

#pragma unroll 1
    for (int kt = 0; kt < 10; ++kt) { KTILE(kt, 1, 8, 1); }
    KTILE(10, 0, 0, 1);
    KTILE(11, 0, -1, 0);

    // epilogue: fused row-max over the clip's 256 visual cols
    // C/D layout (32x32): col = lane&31, row = (reg&3) + 8*(reg>>2) + 4*(lane>>5)
    __syncthreads();
    float* pm = (float*)smem;  // [256 rows][4 wn] partial maxes
#pragma unroll
    for (int mi = 0; mi < 4; ++mi) {
#pragma unroll
        for (int r = 0; r < 16; ++r) {
            float m = fmaxf(acc[mi][0][r], acc[mi][1][r]);
            m = fmaxf(m, __shfl_xor(m, 1, 64));
            m = fmaxf(m, __shfl_xor(m, 2, 64));
            m = fmaxf(m, __shfl_xor(m, 4, 64));
            m = fmaxf(m, __shfl_xor(m, 8, 64));
            m = fmaxf(m, __shfl_xor(m, 16, 64));
            if (lo5 == 0) {
                const int row = wm * 128 + mi * 32 + 4 * hi + (r & 3) + 8 * (r >> 2);
                pm[row * 4 + wn] = m;
            }
        }
    }
    __syncthreads();
    if (tid < 256) {
        float m = fmaxf(fmaxf(pm[tid * 4], pm[tid * 4 + 1]),
                        fmaxf(pm[tid * 4 + 2], pm[tid * 4 + 3]));
        rowmax[(size_t)clip * 16384 + aRow0 + tid] = m;
    }
}

// ---------- kernel 3: mean over 512 audio rows -> clip_sims[32][32] (incl. 1/temp) ----------
__global__ __launch_bounds__(256) void reduce_mean_kernel(const float* __restrict__ rm,
                                                          float* __restrict__ clip) {
    const int b = blockIdx.x >> 5;
    const int c = blockIdx.x & 31;
    const int t = threadIdx.x;
    const float* p = rm + (size_t)c * 16384 + (size_t)b * 512;
    float s = p[t] + p[t + 256];
#pragma unroll
    for (int m = 1; m < 64; m <<= 1) s += __shfl_xor(s, m, 64);
    __shared__ float wsum[4];
    if ((t & 63) == 0) wsum[t >> 6] = s;
    __syncthreads();
    if (t == 0)
        clip[b * 32 + c] = (wsum[0] + wsum[1] + wsum[2] + wsum[3]) * (1.0f / 51.2f);
}

// ---------- kernel 4: log-softmax both ways on 32x32 + scalar loss ----------
__global__ __launch_bounds__(1024) void finalize_kernel(const float* __restrict__ clip,
                                                        float* __restrict__ out) {
    __shared__ float cs[32][33];
    __shared__ float rlse[32], clse[32];
    const int t = threadIdx.x;
    const int b = t >> 5, c = t & 31;
    cs[b][c] = clip[b * 32 + c];
    __syncthreads();
    if (t < 32) {
        float mx = -1e30f;
        for (int j = 0; j < 32; ++j) mx = fmaxf(mx, cs[t][j]);
        float s = 0.0f;
        for (int j = 0; j < 32; ++j) s += expf(cs[t][j] - mx);
        rlse[t] = mx + logf(s);
    } else if (t < 64) {
        const int cc = t - 32;
        float mx = -1e30f;
        for (int j = 0; j < 32; ++j) mx = fmaxf(mx, cs[j][cc]);
        float s = 0.0f;
        for (int j = 0; j < 32; ++j) s += expf(cs[j][cc] - mx);
        clse[cc] = mx + logf(s);
    }
    __syncthreads();
    if (t == 0) {
        float L = 0.0f;
        for (int i = 0; i < 32; ++i)
            L += -0.5f * (2.0f * cs[i][i] - rlse[i] - clse[i]);
        out[0] = L * (1.0f / 32.0f);
    }
}

extern "C" void kernel_launch(void* const* d_in, const int* in_sizes, int n_in,
                              void* d_out, int out_size, void* d_ws, size_t ws_size,
                              hipStream_t stream) {
    const float* audio  = (const float*)d_in[0];   // (32, 512, 768) f32
    const float* visual = (const float*)d_in[1];   // (32, 256, 768) f32

    unsigned short* aN = (unsigned short*)d_ws;                 // 16384*768 bf16
    unsigned short* vN = aN + (size_t)16384 * 768;              // 8192*768 bf16
    float* rowmax = (float*)(vN + (size_t)8192 * 768);          // 32*16384 f32
    float* clip   = rowmax + (size_t)32 * 16384;                // 1024 f32
    float* out    = (float*)d_out;

    l2norm_kernel<<<6144, 256, 0, stream>>>(audio, visual, aN);
    gemm_max_kernel<<<2048, 512, 0, stream>>>(aN, vN, rowmax);
    reduce_mean_kernel<<<1024, 256, 0, stream>>>(rowmax, clip);
    finalize_kernel<<<1, 1024, 0, stream>>>(clip, out);
}